// Round 7
// baseline (347.266 us; speedup 1.0000x reference)
//
#include <hip/hip_runtime.h>
#include <cstddef>
#include <cstdint>

// GCN 2-layer (GCNConv -> BN(train) -> PReLU) x2, N=100000, F=128, E=800000.
// R7: XCD-partitioned CSR build (count+fill): block-group (blockIdx&7) owns a
//     disjoint dst-range, scans all edges, commits only its own -> no cross-XCD
//     line ping-pong on fillc/colw. rowptr doubles as fill cursor (no fillc).

#define EPS_BN 1e-5f
#define BN_BLOCKS 256
#define CSR_BLOCKS 512   // 8 groups x 64 blocks

typedef short short8 __attribute__((ext_vector_type(8)));
typedef float f32x4 __attribute__((ext_vector_type(4)));

static __device__ __forceinline__ unsigned short f2b(float f) {
    union { float f; uint32_t u; } v; v.f = f;
    uint32_t u = v.u;
    return (unsigned short)((u + 0x7FFFu + ((u >> 16) & 1u)) >> 16);
}
static __device__ __forceinline__ float b2f(unsigned short h) {
    union { uint32_t u; float f; } v; v.u = ((uint32_t)h) << 16;
    return v.f;
}
static __device__ __forceinline__ float b2f_s(short h) { return b2f((unsigned short)h); }

// ---------------- degree count, dst-range partitioned by block group ----------------
__global__ __launch_bounds__(256) void k_count(const int* __restrict__ dst, int* __restrict__ cnt,
                                               int E, int N) {
    int g = blockIdx.x & 7;
    int sub = blockIdx.x >> 3;
    int nsub = gridDim.x >> 3;
    int lo = (int)((long)g * N / 8);
    int hi = (int)((long)(g + 1) * N / 8);
    for (int e = sub * 256 + threadIdx.x; e < E; e += nsub * 256) {
        int d = dst[e];
        if (d >= lo && d < hi) atomicAdd(&cnt[d], 1);
    }
}

// ---------------- scan (3 kernels), 1024 elems/block ----------------
__global__ __launch_bounds__(256) void k_scanA(const int* __restrict__ cnt, int* __restrict__ partial, int n) {
    __shared__ int sd[256];
    int tid = threadIdx.x;
    int base = blockIdx.x * 1024 + tid * 4;
    int s = 0;
#pragma unroll
    for (int j = 0; j < 4; j++) { int idx = base + j; if (idx < n) s += cnt[idx]; }
    sd[tid] = s; __syncthreads();
    for (int off = 128; off > 0; off >>= 1) {
        if (tid < off) sd[tid] += sd[tid + off];
        __syncthreads();
    }
    if (tid == 0) partial[blockIdx.x] = sd[0];
}

__global__ __launch_bounds__(128) void k_scanB(int* partial, int nb) {
    __shared__ int sd[128];
    int t = threadIdx.x;
    sd[t] = (t < nb) ? partial[t] : 0;
    __syncthreads();
    for (int off = 1; off < 128; off <<= 1) {
        int v = (t >= off) ? sd[t - off] : 0;
        __syncthreads();
        sd[t] += v;
        __syncthreads();
    }
    if (t < nb) partial[t] = (t == 0) ? 0 : sd[t - 1];
}

// scanC also emits dis = rsqrt(deg+1) (self loop)
__global__ __launch_bounds__(256) void k_scanC(const int* __restrict__ cnt, const int* __restrict__ partial,
                                               int* __restrict__ rowptr, float* __restrict__ dis, int n) {
    __shared__ int sd[256];
    int tid = threadIdx.x;
    int base = blockIdx.x * 1024 + tid * 4;
    int v[4]; int s = 0;
#pragma unroll
    for (int j = 0; j < 4; j++) { int idx = base + j; v[j] = (idx < n) ? cnt[idx] : 0; s += v[j]; }
    sd[tid] = s; __syncthreads();
    for (int off = 1; off < 256; off <<= 1) {
        int u = (tid >= off) ? sd[tid - off] : 0;
        __syncthreads();
        sd[tid] += u;
        __syncthreads();
    }
    int excl = partial[blockIdx.x] + ((tid == 0) ? 0 : sd[tid - 1]);
#pragma unroll
    for (int j = 0; j < 4; j++) {
        int idx = base + j;
        if (idx < n) {
            rowptr[idx] = excl;
            dis[idx] = rsqrtf((float)(v[j] + 1));
        }
        excl += v[j];
    }
}

// ---------------- CSR fill, dst-range partitioned; rowptr is the cursor ----------------
// After this kernel rowptr[d] = row end; agg recovers beg = rowptr[d] - cnt[d].
__global__ __launch_bounds__(256) void k_fill(const int* __restrict__ src, const int* __restrict__ dst,
                                              int* __restrict__ rowptr, int* __restrict__ colw,
                                              int E, int N) {
    int g = blockIdx.x & 7;
    int sub = blockIdx.x >> 3;
    int nsub = gridDim.x >> 3;
    int lo = (int)((long)g * N / 8);
    int hi = (int)((long)(g + 1) * N / 8);
    for (int e = sub * 256 + threadIdx.x; e < E; e += nsub * 256) {
        int d = dst[e];
        if (d >= lo && d < hi) {
            int pos = atomicAdd(&rowptr[d], 1);
            colw[pos] = src[e];
        }
    }
}

// ---------------- W swizzle (both layers): W[o][k] fp32 -> bf16 MFMA B-frag order ----------------
__global__ __launch_bounds__(256) void k_wprep(const float* __restrict__ W1, const float* __restrict__ W2,
                                               unsigned short* __restrict__ Wz1, unsigned short* __restrict__ Wz2) {
    int gi = blockIdx.x * 256 + threadIdx.x;    // 0..32767
    const float* W = (gi < 16384) ? W1 : W2;
    unsigned short* Wz = (gi < 16384) ? Wz1 : Wz2;
    int idx = gi & 16383;
    int o = idx >> 7, k = idx & 127;
    int ct = o >> 4, nn = o & 15, ks = k >> 5, q = (k >> 3) & 3, j = k & 7;
    Wz[(ct * 4 + ks) * 512 + (q * 16 + nn) * 8 + j] = f2b(W[idx]);
}

// ---------------- MFMA GEMM layer1: fp32 X in (converted in-reg), bf16 out ----------------
__global__ __launch_bounds__(256) void k_gemm1(const float* __restrict__ X,
                                               const unsigned short* __restrict__ Wz,
                                               unsigned short* __restrict__ Yb, int n) {
    __shared__ unsigned short lds[16384];   // 32 KB = 32 tiles x 512 shorts
    int tid = threadIdx.x;
    const short8* wsrc = (const short8*)Wz;
    short8* ldst = (short8*)lds;
#pragma unroll
    for (int i = 0; i < 8; i++) ldst[tid + 256 * i] = wsrc[tid + 256 * i];
    __syncthreads();

    int wave = tid >> 6, lane = tid & 63;
    int r0 = blockIdx.x * 64 + wave * 16;
    int mrow = lane & 15, quad = lane >> 4;
    int arow = r0 + mrow; if (arow > n - 1) arow = n - 1;
    const float* xr = X + (size_t)arow * 128;

    f32x4 acc[8];
#pragma unroll
    for (int ct = 0; ct < 8; ct++) acc[ct] = (f32x4){0.f, 0.f, 0.f, 0.f};

#pragma unroll
    for (int ks = 0; ks < 4; ks++) {
        int kb = ks * 32 + quad * 8;
        float4 x0 = *reinterpret_cast<const float4*>(xr + kb);
        float4 x1 = *reinterpret_cast<const float4*>(xr + kb + 4);
        short8 a;
        a[0] = (short)f2b(x0.x); a[1] = (short)f2b(x0.y); a[2] = (short)f2b(x0.z); a[3] = (short)f2b(x0.w);
        a[4] = (short)f2b(x1.x); a[5] = (short)f2b(x1.y); a[6] = (short)f2b(x1.z); a[7] = (short)f2b(x1.w);
#pragma unroll
        for (int ct = 0; ct < 8; ct++) {
            short8 b = *(const short8*)(lds + (ct * 4 + ks) * 512 + lane * 8);
            acc[ct] = __builtin_amdgcn_mfma_f32_16x16x32_bf16(a, b, acc[ct], 0, 0, 0);
        }
    }
    // C layout: col = lane&15, row = quad*4 + i
#pragma unroll
    for (int i = 0; i < 4; i++) {
        int row = r0 + quad * 4 + i;
        if (row < n) {
#pragma unroll
            for (int ct = 0; ct < 8; ct++)
                Yb[(size_t)row * 128 + ct * 16 + mrow] = f2b(acc[ct][i]);
        }
    }
}

// ---------------- MFMA GEMM layer2: bf16 A in with fused BN-apply+PReLU, bf16 out ----------------
__global__ __launch_bounds__(256) void k_gemm2(const unsigned short* __restrict__ Ab,
                                               const unsigned short* __restrict__ Wz,
                                               const float* __restrict__ sc, const float* __restrict__ sh,
                                               const float* __restrict__ ap,
                                               unsigned short* __restrict__ Yb, int n) {
    __shared__ unsigned short lds[16384];
    int tid = threadIdx.x;
    const short8* wsrc = (const short8*)Wz;
    short8* ldst = (short8*)lds;
#pragma unroll
    for (int i = 0; i < 8; i++) ldst[tid + 256 * i] = wsrc[tid + 256 * i];
    __syncthreads();

    float alpha = ap[0];
    int wave = tid >> 6, lane = tid & 63;
    int r0 = blockIdx.x * 64 + wave * 16;
    int mrow = lane & 15, quad = lane >> 4;
    int arow = r0 + mrow; if (arow > n - 1) arow = n - 1;
    const unsigned short* ar = Ab + (size_t)arow * 128;

    f32x4 acc[8];
#pragma unroll
    for (int ct = 0; ct < 8; ct++) acc[ct] = (f32x4){0.f, 0.f, 0.f, 0.f};

#pragma unroll
    for (int ks = 0; ks < 4; ks++) {
        int kb = ks * 32 + quad * 8;
        short8 raw = *(const short8*)(ar + kb);
        float4 s0 = *reinterpret_cast<const float4*>(sc + kb);
        float4 s1 = *reinterpret_cast<const float4*>(sc + kb + 4);
        float4 t0 = *reinterpret_cast<const float4*>(sh + kb);
        float4 t1 = *reinterpret_cast<const float4*>(sh + kb + 4);
        float ss[8] = {s0.x, s0.y, s0.z, s0.w, s1.x, s1.y, s1.z, s1.w};
        float tt[8] = {t0.x, t0.y, t0.z, t0.w, t1.x, t1.y, t1.z, t1.w};
        short8 a;
#pragma unroll
        for (int j = 0; j < 8; j++) {
            float x = fmaf(b2f_s(raw[j]), ss[j], tt[j]);
            x = x > 0.f ? x : alpha * x;
            a[j] = (short)f2b(x);
        }
#pragma unroll
        for (int ct = 0; ct < 8; ct++) {
            short8 b = *(const short8*)(lds + (ct * 4 + ks) * 512 + lane * 8);
            acc[ct] = __builtin_amdgcn_mfma_f32_16x16x32_bf16(a, b, acc[ct], 0, 0, 0);
        }
    }
#pragma unroll
    for (int i = 0; i < 4; i++) {
        int row = r0 + quad * 4 + i;
        if (row < n) {
#pragma unroll
            for (int ct = 0; ct < 8; ct++)
                Yb[(size_t)row * 128 + ct * 16 + mrow] = f2b(acc[ct][i]);
        }
    }
}

// ---------------- aggregation (bf16 H), edge loop unrolled x4 ----------------
// beg = rowptr[node] - cnt[node]  (rowptr holds row END after k_fill).
__global__ __launch_bounds__(256) void k_agg(const unsigned short* __restrict__ Hb,
                                             const int* __restrict__ rowptr, const int* __restrict__ cnt,
                                             const int* __restrict__ colw, const float* __restrict__ dis,
                                             const float* __restrict__ bias,
                                             unsigned short* __restrict__ outb, int n) {
    int lane = threadIdx.x & 15;
    int node = blockIdx.x * 16 + (threadIdx.x >> 4);
    if (node >= n) return;
    int lo = lane * 8;
    float dn = dis[node];
    short8 hv = *(const short8*)(Hb + (size_t)node * 128 + lo);
    float acc[8];
#pragma unroll
    for (int j = 0; j < 8; j++) acc[j] = dn * b2f_s(hv[j]);
    int num = cnt[node];
    int beg = rowptr[node] - num;
    const int* cw = colw + beg;
    int e = 0;
    for (; e + 4 <= num; e += 4) {
        int s0 = cw[e], s1 = cw[e + 1], s2 = cw[e + 2], s3 = cw[e + 3];
        float w0 = dis[s0], w1 = dis[s1], w2 = dis[s2], w3 = dis[s3];
        short8 n0 = *(const short8*)(Hb + (size_t)s0 * 128 + lo);
        short8 n1 = *(const short8*)(Hb + (size_t)s1 * 128 + lo);
        short8 n2 = *(const short8*)(Hb + (size_t)s2 * 128 + lo);
        short8 n3 = *(const short8*)(Hb + (size_t)s3 * 128 + lo);
#pragma unroll
        for (int j = 0; j < 8; j++) {
            acc[j] = fmaf(w0, b2f_s(n0[j]), acc[j]);
            acc[j] = fmaf(w1, b2f_s(n1[j]), acc[j]);
            acc[j] = fmaf(w2, b2f_s(n2[j]), acc[j]);
            acc[j] = fmaf(w3, b2f_s(n3[j]), acc[j]);
        }
    }
    for (; e < num; ++e) {
        int s = cw[e];
        float w = dis[s];
        short8 nb = *(const short8*)(Hb + (size_t)s * 128 + lo);
#pragma unroll
        for (int j = 0; j < 8; j++) acc[j] = fmaf(w, b2f_s(nb[j]), acc[j]);
    }
    const float4 bv0 = reinterpret_cast<const float4*>(bias)[lane * 2 + 0];
    const float4 bv1 = reinterpret_cast<const float4*>(bias)[lane * 2 + 1];
    float bb[8] = {bv0.x, bv0.y, bv0.z, bv0.w, bv1.x, bv1.y, bv1.z, bv1.w};
    short8 ov;
#pragma unroll
    for (int j = 0; j < 8; j++) ov[j] = (short)f2b(fmaf(dn, acc[j], bb[j]));
    *(short8*)(outb + (size_t)node * 128 + lo) = ov;
}

// ---------------- BN stats stage 1: per-block partial sum/sumsq, NO atomics ----------------
__global__ __launch_bounds__(256) void k_bnstats(const unsigned short* __restrict__ X, float* __restrict__ part, int n) {
    __shared__ float ls[16][128];
    __shared__ float lq[16][128];
    int tid = threadIdx.x;
    int rs = tid >> 4, g = tid & 15;
    float s[8], q[8];
#pragma unroll
    for (int j = 0; j < 8; j++) { s[j] = 0.f; q[j] = 0.f; }
#pragma unroll 4
    for (int r = blockIdx.x * 16 + rs; r < n; r += BN_BLOCKS * 16) {
        short8 v = *(const short8*)(X + (size_t)r * 128 + g * 8);
#pragma unroll
        for (int j = 0; j < 8; j++) {
            float f = b2f_s(v[j]);
            s[j] += f; q[j] = fmaf(f, f, q[j]);
        }
    }
#pragma unroll
    for (int j = 0; j < 8; j++) { ls[rs][g * 8 + j] = s[j]; lq[rs][g * 8 + j] = q[j]; }
    __syncthreads();
    for (int off = 8; off > 0; off >>= 1) {
        if (rs < off) {
#pragma unroll
            for (int j = 0; j < 8; j++) {
                ls[rs][g * 8 + j] += ls[rs + off][g * 8 + j];
                lq[rs][g * 8 + j] += lq[rs + off][g * 8 + j];
            }
        }
        __syncthreads();
    }
    if (tid < 128) part[blockIdx.x * 256 + tid] = ls[0][tid];
    else           part[blockIdx.x * 256 + tid] = lq[0][tid - 128];
}

// ---------------- BN stage 2: reduce partials + compute scale/shift ----------------
__global__ __launch_bounds__(128) void k_bnparams(const float* __restrict__ part, const float* __restrict__ g,
                                                  const float* __restrict__ be, float* __restrict__ sc,
                                                  float* __restrict__ sh, float invN) {
    int f = threadIdx.x;
    float s = 0.f, q = 0.f;
#pragma unroll 8
    for (int b = 0; b < BN_BLOCKS; b++) {
        s += part[b * 256 + f];
        q += part[b * 256 + 128 + f];
    }
    float mean = s * invN;
    float var = q * invN - mean * mean;
    float rstd = rsqrtf(var + EPS_BN);
    float scale = g[f] * rstd;
    sc[f] = scale;
    sh[f] = fmaf(-mean, scale, be[f]);
}

// ---------------- final BN apply + PReLU: bf16 in -> fp32 out ----------------
__global__ __launch_bounds__(256) void k_bnact_f(const unsigned short* __restrict__ X, float* __restrict__ Y,
                                                 const float* __restrict__ sc, const float* __restrict__ sh,
                                                 const float* __restrict__ ap, int n8) {
    int i = blockIdx.x * 256 + threadIdx.x;
    if (i >= n8) return;
    float a = ap[0];
    int g = i & 15;
    const float4 s0 = reinterpret_cast<const float4*>(sc)[g * 2 + 0];
    const float4 s1 = reinterpret_cast<const float4*>(sc)[g * 2 + 1];
    const float4 t0 = reinterpret_cast<const float4*>(sh)[g * 2 + 0];
    const float4 t1 = reinterpret_cast<const float4*>(sh)[g * 2 + 1];
    float ss[8] = {s0.x, s0.y, s0.z, s0.w, s1.x, s1.y, s1.z, s1.w};
    float tt[8] = {t0.x, t0.y, t0.z, t0.w, t1.x, t1.y, t1.z, t1.w};
    short8 v = reinterpret_cast<const short8*>(X)[i];
    float out[8];
#pragma unroll
    for (int j = 0; j < 8; j++) {
        float x = fmaf(b2f_s(v[j]), ss[j], tt[j]);
        out[j] = x > 0.f ? x : a * x;
    }
    float4 o0 = {out[0], out[1], out[2], out[3]};
    float4 o1 = {out[4], out[5], out[6], out[7]};
    reinterpret_cast<float4*>(Y)[i * 2 + 0] = o0;
    reinterpret_cast<float4*>(Y)[i * 2 + 1] = o1;
}

extern "C" void kernel_launch(void* const* d_in, const int* in_sizes, int n_in,
                              void* d_out, int out_size, void* d_ws, size_t ws_size,
                              hipStream_t stream) {
    (void)n_in; (void)out_size; (void)ws_size;
    const float* x   = (const float*)d_in[0];
    const int*   ei  = (const int*)d_in[1];
    const float* W1  = (const float*)d_in[2];
    const float* b1  = (const float*)d_in[3];
    const float* g1  = (const float*)d_in[4];
    const float* be1 = (const float*)d_in[5];
    const float* W2  = (const float*)d_in[6];
    const float* b2  = (const float*)d_in[7];
    const float* g2  = (const float*)d_in[8];
    const float* be2 = (const float*)d_in[9];
    const float* ap  = (const float*)d_in[10];
    float* out = (float*)d_out;

    const int N = in_sizes[0] / 128;
    const int E = in_sizes[1] / 2;
    const int* srcIdx = ei;        // edge_index[0]
    const int* dstIdx = ei + E;    // edge_index[1]

    // ---- workspace layout ----
    char* w = (char*)d_ws;
    size_t off = 0;
    auto alloc = [&](size_t bytes) { char* p = w + off; off += (bytes + 255) & ~(size_t)255; return p; };
    int*   cnt     = (int*)  alloc((size_t)N * 4);
    int*   rowptr  = (int*)  alloc((size_t)N * 4);
    int*   colw    = (int*)  alloc((size_t)E * 4);
    float* dis     = (float*)alloc((size_t)N * 4);
    int*   partial = (int*)  alloc(4096);
    float* part    = (float*)alloc((size_t)BN_BLOCKS * 256 * 4);
    float* sc1     = (float*)alloc(512);
    float* sh1     = (float*)alloc(512);
    float* sc2     = (float*)alloc(512);
    float* sh2     = (float*)alloc(512);
    unsigned short* Wz1 = (unsigned short*)alloc(16384 * 2);
    unsigned short* Wz2 = (unsigned short*)alloc(16384 * 2);
    unsigned short* bufH = (unsigned short*)alloc((size_t)N * 128 * 2);   // h1 -> h2
    unsigned short* bufA = (unsigned short*)alloc((size_t)N * 128 * 2);   // a1 -> a2

    const float invN = 1.0f / (float)N;
    const int NB = (N + 1023) / 1024;
    const int n8 = N * 16;    // short8 groups per buffer
    const int gGemm = (N + 63) / 64;
    const int gAgg  = (N + 15) / 16;

    hipMemsetAsync(cnt, 0, (size_t)N * 4, stream);

    // weight prep (both layers, one launch)
    k_wprep<<<128, 256, 0, stream>>>(W1, W2, Wz1, Wz2);

    // degree + CSR (XCD-partitioned count/fill; dis fused into scanC)
    k_count<<<CSR_BLOCKS, 256, 0, stream>>>(dstIdx, cnt, E, N);
    k_scanA<<<NB, 256, 0, stream>>>(cnt, partial, N);
    k_scanB<<<1, 128, 0, stream>>>(partial, NB);
    k_scanC<<<NB, 256, 0, stream>>>(cnt, partial, rowptr, dis, N);
    k_fill<<<CSR_BLOCKS, 256, 0, stream>>>(srcIdx, dstIdx, rowptr, colw, E, N);

    // ---- layer 1 ----
    k_gemm1<<<gGemm, 256, 0, stream>>>(x, Wz1, bufH, N);                           // h1 -> bufH
    k_agg<<<gAgg, 256, 0, stream>>>(bufH, rowptr, cnt, colw, dis, b1, bufA, N);    // a1 -> bufA
    k_bnstats<<<BN_BLOCKS, 256, 0, stream>>>(bufA, part, N);
    k_bnparams<<<1, 128, 0, stream>>>(part, g1, be1, sc1, sh1, invN);

    // ---- layer 2 (act1 fused into gemm2 A-load) ----
    k_gemm2<<<gGemm, 256, 0, stream>>>(bufA, Wz2, sc1, sh1, ap, bufH, N);          // h2 -> bufH
    k_agg<<<gAgg, 256, 0, stream>>>(bufH, rowptr, cnt, colw, dis, b2, bufA, N);    // a2 -> bufA
    k_bnstats<<<BN_BLOCKS, 256, 0, stream>>>(bufA, part, N);
    k_bnparams<<<1, 128, 0, stream>>>(part, g2, be2, sc2, sh2, invN);
    k_bnact_f<<<(n8 + 255) / 256, 256, 0, stream>>>(bufA, out, sc2, sh2, ap, n8);  // -> d_out fp32
}

// Round 8
// 317.347 us; speedup vs baseline: 1.0943x; 1.0943x over previous
//
#include <hip/hip_runtime.h>
#include <cstddef>
#include <cstdint>

// GCN 2-layer (GCNConv -> BN(train) -> PReLU) x2, N=100000, F=128, E=800000.
// R8: atomic-free CSR fill via rank trick — count-phase atomicAdd returns the
//     per-dst rank, persisted to rank[e]; fill is then pure scattered stores
//     (no dependent atomic round-trip). Single pass over edges in each kernel.

#define EPS_BN 1e-5f
#define BN_BLOCKS 256

typedef short short8 __attribute__((ext_vector_type(8)));
typedef float f32x4 __attribute__((ext_vector_type(4)));

static __device__ __forceinline__ unsigned short f2b(float f) {
    union { float f; uint32_t u; } v; v.f = f;
    uint32_t u = v.u;
    return (unsigned short)((u + 0x7FFFu + ((u >> 16) & 1u)) >> 16);
}
static __device__ __forceinline__ float b2f(unsigned short h) {
    union { uint32_t u; float f; } v; v.u = ((uint32_t)h) << 16;
    return v.f;
}
static __device__ __forceinline__ float b2f_s(short h) { return b2f((unsigned short)h); }

// ---------------- degree count + rank capture ----------------
__global__ __launch_bounds__(256) void k_count(const int* __restrict__ dst, int* __restrict__ cnt,
                                               int* __restrict__ rank, int E) {
    int e = blockIdx.x * 256 + threadIdx.x;
    if (e < E) rank[e] = atomicAdd(&cnt[dst[e]], 1);
}

// ---------------- scan (3 kernels), 1024 elems/block ----------------
__global__ __launch_bounds__(256) void k_scanA(const int* __restrict__ cnt, int* __restrict__ partial, int n) {
    __shared__ int sd[256];
    int tid = threadIdx.x;
    int base = blockIdx.x * 1024 + tid * 4;
    int s = 0;
#pragma unroll
    for (int j = 0; j < 4; j++) { int idx = base + j; if (idx < n) s += cnt[idx]; }
    sd[tid] = s; __syncthreads();
    for (int off = 128; off > 0; off >>= 1) {
        if (tid < off) sd[tid] += sd[tid + off];
        __syncthreads();
    }
    if (tid == 0) partial[blockIdx.x] = sd[0];
}

__global__ __launch_bounds__(128) void k_scanB(int* partial, int nb) {
    __shared__ int sd[128];
    int t = threadIdx.x;
    sd[t] = (t < nb) ? partial[t] : 0;
    __syncthreads();
    for (int off = 1; off < 128; off <<= 1) {
        int v = (t >= off) ? sd[t - off] : 0;
        __syncthreads();
        sd[t] += v;
        __syncthreads();
    }
    if (t < nb) partial[t] = (t == 0) ? 0 : sd[t - 1];
}

// scanC also emits dis = rsqrt(deg+1) (self loop); rowptr = exclusive start
__global__ __launch_bounds__(256) void k_scanC(const int* __restrict__ cnt, const int* __restrict__ partial,
                                               int* __restrict__ rowptr, float* __restrict__ dis, int n) {
    __shared__ int sd[256];
    int tid = threadIdx.x;
    int base = blockIdx.x * 1024 + tid * 4;
    int v[4]; int s = 0;
#pragma unroll
    for (int j = 0; j < 4; j++) { int idx = base + j; v[j] = (idx < n) ? cnt[idx] : 0; s += v[j]; }
    sd[tid] = s; __syncthreads();
    for (int off = 1; off < 256; off <<= 1) {
        int u = (tid >= off) ? sd[tid - off] : 0;
        __syncthreads();
        sd[tid] += u;
        __syncthreads();
    }
    int excl = partial[blockIdx.x] + ((tid == 0) ? 0 : sd[tid - 1]);
#pragma unroll
    for (int j = 0; j < 4; j++) {
        int idx = base + j;
        if (idx < n) {
            rowptr[idx] = excl;
            dis[idx] = rsqrtf((float)(v[j] + 1));
        }
        excl += v[j];
    }
}

// ---------------- CSR fill, NO atomics: pos = rowptr[dst] + rank[e] ----------------
__global__ __launch_bounds__(256) void k_fill(const int* __restrict__ src, const int* __restrict__ dst,
                                              const int* __restrict__ rowptr, const int* __restrict__ rank,
                                              int* __restrict__ colw, int E) {
    int e = blockIdx.x * 256 + threadIdx.x;
    if (e < E) {
        int d = dst[e];
        colw[rowptr[d] + rank[e]] = src[e];
    }
}

// ---------------- W swizzle (both layers): W[o][k] fp32 -> bf16 MFMA B-frag order ----------------
__global__ __launch_bounds__(256) void k_wprep(const float* __restrict__ W1, const float* __restrict__ W2,
                                               unsigned short* __restrict__ Wz1, unsigned short* __restrict__ Wz2) {
    int gi = blockIdx.x * 256 + threadIdx.x;    // 0..32767
    const float* W = (gi < 16384) ? W1 : W2;
    unsigned short* Wz = (gi < 16384) ? Wz1 : Wz2;
    int idx = gi & 16383;
    int o = idx >> 7, k = idx & 127;
    int ct = o >> 4, nn = o & 15, ks = k >> 5, q = (k >> 3) & 3, j = k & 7;
    Wz[(ct * 4 + ks) * 512 + (q * 16 + nn) * 8 + j] = f2b(W[idx]);
}

// ---------------- MFMA GEMM layer1: fp32 X in (converted in-reg), bf16 out ----------------
__global__ __launch_bounds__(256) void k_gemm1(const float* __restrict__ X,
                                               const unsigned short* __restrict__ Wz,
                                               unsigned short* __restrict__ Yb, int n) {
    __shared__ unsigned short lds[16384];   // 32 KB = 32 tiles x 512 shorts
    int tid = threadIdx.x;
    const short8* wsrc = (const short8*)Wz;
    short8* ldst = (short8*)lds;
#pragma unroll
    for (int i = 0; i < 8; i++) ldst[tid + 256 * i] = wsrc[tid + 256 * i];
    __syncthreads();

    int wave = tid >> 6, lane = tid & 63;
    int r0 = blockIdx.x * 64 + wave * 16;
    int mrow = lane & 15, quad = lane >> 4;
    int arow = r0 + mrow; if (arow > n - 1) arow = n - 1;
    const float* xr = X + (size_t)arow * 128;

    f32x4 acc[8];
#pragma unroll
    for (int ct = 0; ct < 8; ct++) acc[ct] = (f32x4){0.f, 0.f, 0.f, 0.f};

#pragma unroll
    for (int ks = 0; ks < 4; ks++) {
        int kb = ks * 32 + quad * 8;
        float4 x0 = *reinterpret_cast<const float4*>(xr + kb);
        float4 x1 = *reinterpret_cast<const float4*>(xr + kb + 4);
        short8 a;
        a[0] = (short)f2b(x0.x); a[1] = (short)f2b(x0.y); a[2] = (short)f2b(x0.z); a[3] = (short)f2b(x0.w);
        a[4] = (short)f2b(x1.x); a[5] = (short)f2b(x1.y); a[6] = (short)f2b(x1.z); a[7] = (short)f2b(x1.w);
#pragma unroll
        for (int ct = 0; ct < 8; ct++) {
            short8 b = *(const short8*)(lds + (ct * 4 + ks) * 512 + lane * 8);
            acc[ct] = __builtin_amdgcn_mfma_f32_16x16x32_bf16(a, b, acc[ct], 0, 0, 0);
        }
    }
    // C layout: col = lane&15, row = quad*4 + i
#pragma unroll
    for (int i = 0; i < 4; i++) {
        int row = r0 + quad * 4 + i;
        if (row < n) {
#pragma unroll
            for (int ct = 0; ct < 8; ct++)
                Yb[(size_t)row * 128 + ct * 16 + mrow] = f2b(acc[ct][i]);
        }
    }
}

// ---------------- MFMA GEMM layer2: bf16 A in with fused BN-apply+PReLU, bf16 out ----------------
__global__ __launch_bounds__(256) void k_gemm2(const unsigned short* __restrict__ Ab,
                                               const unsigned short* __restrict__ Wz,
                                               const float* __restrict__ sc, const float* __restrict__ sh,
                                               const float* __restrict__ ap,
                                               unsigned short* __restrict__ Yb, int n) {
    __shared__ unsigned short lds[16384];
    int tid = threadIdx.x;
    const short8* wsrc = (const short8*)Wz;
    short8* ldst = (short8*)lds;
#pragma unroll
    for (int i = 0; i < 8; i++) ldst[tid + 256 * i] = wsrc[tid + 256 * i];
    __syncthreads();

    float alpha = ap[0];
    int wave = tid >> 6, lane = tid & 63;
    int r0 = blockIdx.x * 64 + wave * 16;
    int mrow = lane & 15, quad = lane >> 4;
    int arow = r0 + mrow; if (arow > n - 1) arow = n - 1;
    const unsigned short* ar = Ab + (size_t)arow * 128;

    f32x4 acc[8];
#pragma unroll
    for (int ct = 0; ct < 8; ct++) acc[ct] = (f32x4){0.f, 0.f, 0.f, 0.f};

#pragma unroll
    for (int ks = 0; ks < 4; ks++) {
        int kb = ks * 32 + quad * 8;
        short8 raw = *(const short8*)(ar + kb);
        float4 s0 = *reinterpret_cast<const float4*>(sc + kb);
        float4 s1 = *reinterpret_cast<const float4*>(sc + kb + 4);
        float4 t0 = *reinterpret_cast<const float4*>(sh + kb);
        float4 t1 = *reinterpret_cast<const float4*>(sh + kb + 4);
        float ss[8] = {s0.x, s0.y, s0.z, s0.w, s1.x, s1.y, s1.z, s1.w};
        float tt[8] = {t0.x, t0.y, t0.z, t0.w, t1.x, t1.y, t1.z, t1.w};
        short8 a;
#pragma unroll
        for (int j = 0; j < 8; j++) {
            float x = fmaf(b2f_s(raw[j]), ss[j], tt[j]);
            x = x > 0.f ? x : alpha * x;
            a[j] = (short)f2b(x);
        }
#pragma unroll
        for (int ct = 0; ct < 8; ct++) {
            short8 b = *(const short8*)(lds + (ct * 4 + ks) * 512 + lane * 8);
            acc[ct] = __builtin_amdgcn_mfma_f32_16x16x32_bf16(a, b, acc[ct], 0, 0, 0);
        }
    }
#pragma unroll
    for (int i = 0; i < 4; i++) {
        int row = r0 + quad * 4 + i;
        if (row < n) {
#pragma unroll
            for (int ct = 0; ct < 8; ct++)
                Yb[(size_t)row * 128 + ct * 16 + mrow] = f2b(acc[ct][i]);
        }
    }
}

// ---------------- aggregation (bf16 H), edge loop unrolled x4 ----------------
__global__ __launch_bounds__(256) void k_agg(const unsigned short* __restrict__ Hb,
                                             const int* __restrict__ rowptr, const int* __restrict__ cnt,
                                             const int* __restrict__ colw, const float* __restrict__ dis,
                                             const float* __restrict__ bias,
                                             unsigned short* __restrict__ outb, int n) {
    int lane = threadIdx.x & 15;
    int node = blockIdx.x * 16 + (threadIdx.x >> 4);
    if (node >= n) return;
    int lo = lane * 8;
    float dn = dis[node];
    short8 hv = *(const short8*)(Hb + (size_t)node * 128 + lo);
    float acc[8];
#pragma unroll
    for (int j = 0; j < 8; j++) acc[j] = dn * b2f_s(hv[j]);
    int num = cnt[node];
    int beg = rowptr[node];
    const int* cw = colw + beg;
    int e = 0;
    for (; e + 4 <= num; e += 4) {
        int s0 = cw[e], s1 = cw[e + 1], s2 = cw[e + 2], s3 = cw[e + 3];
        float w0 = dis[s0], w1 = dis[s1], w2 = dis[s2], w3 = dis[s3];
        short8 n0 = *(const short8*)(Hb + (size_t)s0 * 128 + lo);
        short8 n1 = *(const short8*)(Hb + (size_t)s1 * 128 + lo);
        short8 n2 = *(const short8*)(Hb + (size_t)s2 * 128 + lo);
        short8 n3 = *(const short8*)(Hb + (size_t)s3 * 128 + lo);
#pragma unroll
        for (int j = 0; j < 8; j++) {
            acc[j] = fmaf(w0, b2f_s(n0[j]), acc[j]);
            acc[j] = fmaf(w1, b2f_s(n1[j]), acc[j]);
            acc[j] = fmaf(w2, b2f_s(n2[j]), acc[j]);
            acc[j] = fmaf(w3, b2f_s(n3[j]), acc[j]);
        }
    }
    for (; e < num; ++e) {
        int s = cw[e];
        float w = dis[s];
        short8 nb = *(const short8*)(Hb + (size_t)s * 128 + lo);
#pragma unroll
        for (int j = 0; j < 8; j++) acc[j] = fmaf(w, b2f_s(nb[j]), acc[j]);
    }
    const float4 bv0 = reinterpret_cast<const float4*>(bias)[lane * 2 + 0];
    const float4 bv1 = reinterpret_cast<const float4*>(bias)[lane * 2 + 1];
    float bb[8] = {bv0.x, bv0.y, bv0.z, bv0.w, bv1.x, bv1.y, bv1.z, bv1.w};
    short8 ov;
#pragma unroll
    for (int j = 0; j < 8; j++) ov[j] = (short)f2b(fmaf(dn, acc[j], bb[j]));
    *(short8*)(outb + (size_t)node * 128 + lo) = ov;
}

// ---------------- BN stats stage 1: per-block partial sum/sumsq, NO atomics ----------------
__global__ __launch_bounds__(256) void k_bnstats(const unsigned short* __restrict__ X, float* __restrict__ part, int n) {
    __shared__ float ls[16][128];
    __shared__ float lq[16][128];
    int tid = threadIdx.x;
    int rs = tid >> 4, g = tid & 15;
    float s[8], q[8];
#pragma unroll
    for (int j = 0; j < 8; j++) { s[j] = 0.f; q[j] = 0.f; }
#pragma unroll 4
    for (int r = blockIdx.x * 16 + rs; r < n; r += BN_BLOCKS * 16) {
        short8 v = *(const short8*)(X + (size_t)r * 128 + g * 8);
#pragma unroll
        for (int j = 0; j < 8; j++) {
            float f = b2f_s(v[j]);
            s[j] += f; q[j] = fmaf(f, f, q[j]);
        }
    }
#pragma unroll
    for (int j = 0; j < 8; j++) { ls[rs][g * 8 + j] = s[j]; lq[rs][g * 8 + j] = q[j]; }
    __syncthreads();
    for (int off = 8; off > 0; off >>= 1) {
        if (rs < off) {
#pragma unroll
            for (int j = 0; j < 8; j++) {
                ls[rs][g * 8 + j] += ls[rs + off][g * 8 + j];
                lq[rs][g * 8 + j] += lq[rs + off][g * 8 + j];
            }
        }
        __syncthreads();
    }
    if (tid < 128) part[blockIdx.x * 256 + tid] = ls[0][tid];
    else           part[blockIdx.x * 256 + tid] = lq[0][tid - 128];
}

// ---------------- BN stage 2: reduce partials + compute scale/shift ----------------
__global__ __launch_bounds__(128) void k_bnparams(const float* __restrict__ part, const float* __restrict__ g,
                                                  const float* __restrict__ be, float* __restrict__ sc,
                                                  float* __restrict__ sh, float invN) {
    int f = threadIdx.x;
    float s = 0.f, q = 0.f;
#pragma unroll 8
    for (int b = 0; b < BN_BLOCKS; b++) {
        s += part[b * 256 + f];
        q += part[b * 256 + 128 + f];
    }
    float mean = s * invN;
    float var = q * invN - mean * mean;
    float rstd = rsqrtf(var + EPS_BN);
    float scale = g[f] * rstd;
    sc[f] = scale;
    sh[f] = fmaf(-mean, scale, be[f]);
}

// ---------------- final BN apply + PReLU: bf16 in -> fp32 out ----------------
__global__ __launch_bounds__(256) void k_bnact_f(const unsigned short* __restrict__ X, float* __restrict__ Y,
                                                 const float* __restrict__ sc, const float* __restrict__ sh,
                                                 const float* __restrict__ ap, int n8) {
    int i = blockIdx.x * 256 + threadIdx.x;
    if (i >= n8) return;
    float a = ap[0];
    int g = i & 15;
    const float4 s0 = reinterpret_cast<const float4*>(sc)[g * 2 + 0];
    const float4 s1 = reinterpret_cast<const float4*>(sc)[g * 2 + 1];
    const float4 t0 = reinterpret_cast<const float4*>(sh)[g * 2 + 0];
    const float4 t1 = reinterpret_cast<const float4*>(sh)[g * 2 + 1];
    float ss[8] = {s0.x, s0.y, s0.z, s0.w, s1.x, s1.y, s1.z, s1.w};
    float tt[8] = {t0.x, t0.y, t0.z, t0.w, t1.x, t1.y, t1.z, t1.w};
    short8 v = reinterpret_cast<const short8*>(X)[i];
    float out[8];
#pragma unroll
    for (int j = 0; j < 8; j++) {
        float x = fmaf(b2f_s(v[j]), ss[j], tt[j]);
        out[j] = x > 0.f ? x : a * x;
    }
    float4 o0 = {out[0], out[1], out[2], out[3]};
    float4 o1 = {out[4], out[5], out[6], out[7]};
    reinterpret_cast<float4*>(Y)[i * 2 + 0] = o0;
    reinterpret_cast<float4*>(Y)[i * 2 + 1] = o1;
}

extern "C" void kernel_launch(void* const* d_in, const int* in_sizes, int n_in,
                              void* d_out, int out_size, void* d_ws, size_t ws_size,
                              hipStream_t stream) {
    (void)n_in; (void)out_size; (void)ws_size;
    const float* x   = (const float*)d_in[0];
    const int*   ei  = (const int*)d_in[1];
    const float* W1  = (const float*)d_in[2];
    const float* b1  = (const float*)d_in[3];
    const float* g1  = (const float*)d_in[4];
    const float* be1 = (const float*)d_in[5];
    const float* W2  = (const float*)d_in[6];
    const float* b2  = (const float*)d_in[7];
    const float* g2  = (const float*)d_in[8];
    const float* be2 = (const float*)d_in[9];
    const float* ap  = (const float*)d_in[10];
    float* out = (float*)d_out;

    const int N = in_sizes[0] / 128;
    const int E = in_sizes[1] / 2;
    const int* srcIdx = ei;        // edge_index[0]
    const int* dstIdx = ei + E;    // edge_index[1]

    // ---- workspace layout ----
    char* w = (char*)d_ws;
    size_t off = 0;
    auto alloc = [&](size_t bytes) { char* p = w + off; off += (bytes + 255) & ~(size_t)255; return p; };
    int*   cnt     = (int*)  alloc((size_t)N * 4);
    int*   rowptr  = (int*)  alloc((size_t)N * 4);
    int*   rank    = (int*)  alloc((size_t)E * 4);
    int*   colw    = (int*)  alloc((size_t)E * 4);
    float* dis     = (float*)alloc((size_t)N * 4);
    int*   partial = (int*)  alloc(4096);
    float* part    = (float*)alloc((size_t)BN_BLOCKS * 256 * 4);
    float* sc1     = (float*)alloc(512);
    float* sh1     = (float*)alloc(512);
    float* sc2     = (float*)alloc(512);
    float* sh2     = (float*)alloc(512);
    unsigned short* Wz1 = (unsigned short*)alloc(16384 * 2);
    unsigned short* Wz2 = (unsigned short*)alloc(16384 * 2);
    unsigned short* bufH = (unsigned short*)alloc((size_t)N * 128 * 2);   // h1 -> h2
    unsigned short* bufA = (unsigned short*)alloc((size_t)N * 128 * 2);   // a1 -> a2

    const float invN = 1.0f / (float)N;
    const int NB = (N + 1023) / 1024;
    const int gE = (E + 255) / 256;
    const int n8 = N * 16;    // short8 groups per buffer
    const int gGemm = (N + 63) / 64;
    const int gAgg  = (N + 15) / 16;

    hipMemsetAsync(cnt, 0, (size_t)N * 4, stream);

    // weight prep (both layers, one launch)
    k_wprep<<<128, 256, 0, stream>>>(W1, W2, Wz1, Wz2);

    // degree + rank + CSR (fill has NO atomics)
    k_count<<<gE, 256, 0, stream>>>(dstIdx, cnt, rank, E);
    k_scanA<<<NB, 256, 0, stream>>>(cnt, partial, N);
    k_scanB<<<1, 128, 0, stream>>>(partial, NB);
    k_scanC<<<NB, 256, 0, stream>>>(cnt, partial, rowptr, dis, N);
    k_fill<<<gE, 256, 0, stream>>>(srcIdx, dstIdx, rowptr, rank, colw, E);

    // ---- layer 1 ----
    k_gemm1<<<gGemm, 256, 0, stream>>>(x, Wz1, bufH, N);                           // h1 -> bufH
    k_agg<<<gAgg, 256, 0, stream>>>(bufH, rowptr, cnt, colw, dis, b1, bufA, N);    // a1 -> bufA
    k_bnstats<<<BN_BLOCKS, 256, 0, stream>>>(bufA, part, N);
    k_bnparams<<<1, 128, 0, stream>>>(part, g1, be1, sc1, sh1, invN);

    // ---- layer 2 (act1 fused into gemm2 A-load) ----
    k_gemm2<<<gGemm, 256, 0, stream>>>(bufA, Wz2, sc1, sh1, ap, bufH, N);          // h2 -> bufH
    k_agg<<<gAgg, 256, 0, stream>>>(bufH, rowptr, cnt, colw, dis, b2, bufA, N);    // a2 -> bufA
    k_bnstats<<<BN_BLOCKS, 256, 0, stream>>>(bufA, part, N);
    k_bnparams<<<1, 128, 0, stream>>>(part, g2, be2, sc2, sh2, invN);
    k_bnact_f<<<(n8 + 255) / 256, 256, 0, stream>>>(bufA, out, sc2, sh2, ap, n8);  // -> d_out fp32
}